// Round 10
// baseline (1295.561 us; speedup 1.0000x reference)
//
#include <hip/hip_runtime.h>
#include <math.h>

// ResBlock via bf16 MFMA implicit-GEMM conv3x3.
// R10: ONE barrier region per (ci,kh) sub-step with rolling counted lgkmcnt:
//   issue 20 ds_reads (kw0,kw1) + staging gl_lds; lgkm(10)->MFMA(kw0);
//   issue 10 (kw2); lgkm(10)->MFMA(kw1); lgkm(0)->MFMA(kw2); vmcnt(N); bar.
// LDS pipe streams later-kw reads under earlier MFMA bursts -> pipes overlap
// (R6/R9 post-mortem: per-phase barrier lockstep serialized LDS and MFMA).
// s_w TRIPLE-buffered (staged 2 sub-steps ahead), s_x double (1 chunk ahead);
// all drains counted, never blocking on just-issued loads.
// B=16, C=256, H=W=96. Padded channels-last bf16 intermediates [16][98][98][256].

#define Bn 16
#define Cn 256
#define Hn 96
#define Wn 96
#define PH 98
#define PW 98
#define HW (Hn*Wn)

typedef __bf16 bf16x8 __attribute__((ext_vector_type(8)));
typedef float  f32x4  __attribute__((ext_vector_type(4)));

__device__ __forceinline__ unsigned short f2bf(float f) {
    unsigned int u = __float_as_uint(f);
    unsigned int r = (u + 0x7fffu + ((u >> 16) & 1u)) >> 16;
    return (unsigned short)r;
}

__device__ __forceinline__ void lds_load16(void* lds, const void* g) {
    auto gp = (const __attribute__((address_space(1))) char*)(unsigned long long)(uintptr_t)g;
    auto lp = (__attribute__((address_space(3))) char*)(unsigned int)(uintptr_t)lds;
    __builtin_amdgcn_global_load_lds(gp, lp, 16, 0, 0);
}

#define SB() __builtin_amdgcn_sched_barrier(0)
#define MEMFENCE() asm volatile("" ::: "memory")

// ---- zero the padded border of a CL tensor ----
__global__ __launch_bounds__(256)
void zero_border_k(unsigned short* __restrict__ t) {
    int idx = blockIdx.x * 256 + threadIdx.x;      // 16*388*32 threads
    int oct = idx & 31;
    int rest = idx >> 5;
    int pidx = rest % 388;
    int b = rest / 388;
    int h, w;
    if (pidx < 98)       { h = 0;  w = pidx; }
    else if (pidx < 196) { h = 97; w = pidx - 98; }
    else if (pidx < 292) { h = pidx - 196 + 1; w = 0; }
    else                 { h = pidx - 292 + 1; w = 97; }
    size_t e = ((size_t)(b * PH + h) * PW + w) * 256 + oct * 8;
    *(uint4*)(t + e) = make_uint4(0u, 0u, 0u, 0u);
}

// ---- pack weights fp32 [co][ci][3][3] -> bf16 [cc][k9][c'][ci32] ----
template<bool PERM>
__global__ __launch_bounds__(256)
void pack_w_k(const float* __restrict__ w, unsigned short* __restrict__ wp) {
    int idx = blockIdx.x * 256 + threadIdx.x;      // 589824
    int ci_l = idx & 31;
    int c    = (idx >> 5) & 255;
    int v    = idx >> 13;          // 0..71
    int k9   = v % 9;
    int cc   = v / 9;
    int co;
    if (PERM) {
        co = (c < 86) ? c * 3 : (c < 171) ? (c - 86) * 3 + 1 : (c - 171) * 3 + 2;
    } else {
        co = c;
    }
    float val = w[((size_t)co * 256 + cc * 32 + ci_l) * 9 + k9];
    wp[idx] = f2bf(val);
}

// ---- x fp32 NCHW -> padded channels-last bf16 (interior only) ----
__global__ __launch_bounds__(256)
void transform_x_k(const float* __restrict__ x, unsigned short* __restrict__ xp) {
    __shared__ float s[32 * 33];
    const int t = threadIdx.x;
    const int col0 = blockIdx.x * 32;
    const int row  = blockIdx.y;
    const int z = blockIdx.z;
    const int b = z >> 3;
    const int ci0 = (z & 7) * 32;

    #pragma unroll
    for (int i = 0; i < 4; ++i) {
        int ci = i * 8 + (t >> 5);
        int px = t & 31;
        s[ci * 33 + px] = x[((size_t)(b * Cn + ci0 + ci)) * HW + row * Wn + col0 + px];
    }
    __syncthreads();
    const int px = t >> 3;
    const int c4 = (t & 7) * 4;
    ushort4 o;
    o.x = f2bf(s[(c4 + 0) * 33 + px]);
    o.y = f2bf(s[(c4 + 1) * 33 + px]);
    o.z = f2bf(s[(c4 + 2) * 33 + px]);
    o.w = f2bf(s[(c4 + 3) * 33 + px]);
    size_t e = ((size_t)(b * PH + row + 1) * PW + (col0 + px + 1)) * 256 + ci0 + c4;
    *(ushort4*)(xp + e) = o;
}

// ---- Pipelined MFMA conv3x3 ----
// 512 threads (8 waves), 1 block/CU. Block: 128 co x (12x32 px).
// Staging via global_load_lds, PRE-SWIZZLED SOURCE (rule #21), involution
// phys16Bslot = logical ^ ((logical>>3)&3) on both tensors.
// Staging schedule (regions = sub-steps s=3c+kh):
//   kh0: w(3c+2)->wbuf2 (3 slices) + x(c+1) slices 0-2  [if c<7]
//   kh1: w(3c+3)->wbuf0 [if c<7]   + x(c+1) slice 3     [if c<7]
//   kh2: w(3c+4)->wbuf1 [if c<7]
// End-of-region drains (FIFO-exact): kh0: vmcnt(6)|c7:3; kh1: vmcnt(7)|c7:0;
// kh2: vmcnt(3)|c7:0.
template<int MODE>
__global__ __launch_bounds__(512) __attribute__((amdgpu_waves_per_eu(2, 2)))
void conv_k(const unsigned short* __restrict__ in_cl,
            const unsigned short* __restrict__ wp,
            const float* __restrict__ prelu_w,
            const float* __restrict__ xres,
            void* __restrict__ outp)
{
    __shared__ unsigned short s_x[2][2048 * 8];   // 2 x 32768 B [px(14x34)][ci32]
    __shared__ unsigned short s_w[3][1536 * 8];   // 3 x 24576 B [kw3][co128][ci32]

    const int tid = threadIdx.x;
    const int bid = blockIdx.x;
    // XCD-chunked bijective swizzle (768 = 8 * 96); co-half fastest.
    const int wg = (bid & 7) * 96 + (bid >> 3);
    const int blk_co = (wg & 1) * 128;
    const int t2 = wg >> 1;                // 0..383
    const int tile = t2 % 24;
    const int b = t2 / 24;
    const int R0 = (tile / 3) * 12;        // padded-coord halo base row
    const int C0 = (tile % 3) * 32;

    const int lane = tid & 63;
    const int wv = tid >> 6;
    const int l15 = lane & 15;
    const int qq = lane >> 4;
    const int cg = wv & 1;
    const int wrow = wv >> 1;
    const int qa = qq ^ ((l15 >> 1) & 3);  // swizzled 16B-slot for af reads

    const unsigned short* img = in_cl + (size_t)b * PH * PW * 256;

    // ---- staging maps (gl_lds dest linear = i*512+tid; source pre-swizzled) ----
    int xg[4];
    #pragma unroll
    for (int i = 0; i < 4; ++i) {
        int slot = i * 512 + tid;
        int lsl = slot ^ ((slot >> 3) & 3);    // involution, preserves slot>>3
        if (lsl > 1903) lsl = 1903;            // junk phys slots read a safe dup
        int p = lsl >> 2;
        int pr = p / 34, pc = p - pr * 34;
        xg[i] = ((R0 + pr) * PW + (C0 + pc)) * 256 + (lsl & 3) * 8;
    }
    int wbase[3];
    #pragma unroll
    for (int i = 0; i < 3; ++i) {
        int slot = i * 512 + tid;
        int lsl = slot ^ ((slot >> 3) & 3);    // stays in [0,1536)
        int kw = lsl >> 9;
        int co = (lsl >> 2) & 127;
        wbase[i] = kw * 8192 + (blk_co + co) * 32 + (lsl & 3) * 8;
    }

    f32x4 acc[4][6];
    #pragma unroll
    for (int m = 0; m < 4; ++m)
        #pragma unroll
        for (int n = 0; n < 6; ++n) acc[m][n] = 0.f;

    // ---- prologue: w(0)->wbuf0, w(1)->wbuf1, x(0)->xbuf0; full drain ----
    #pragma unroll
    for (int i = 0; i < 3; ++i) lds_load16(&s_w[0][(size_t)(i * 512 + tid) * 8], wp + wbase[i]);
    #pragma unroll
    for (int i = 0; i < 3; ++i) lds_load16(&s_w[1][(size_t)(i * 512 + tid) * 8], wp + 24576 + wbase[i]);
    #pragma unroll
    for (int i = 0; i < 4; ++i) lds_load16(&s_x[0][(size_t)(i * 512 + tid) * 8], img + xg[i]);
    MEMFENCE(); SB();
    asm volatile("s_waitcnt vmcnt(0)" ::: "memory");
    SB();
    __builtin_amdgcn_s_barrier();
    SB();

#define LOADF(AF, BF, KH, KW) {                                                   \
    _Pragma("unroll")                                                             \
    for (int m = 0; m < 4; ++m) {                                                 \
        const int row_ = (KW) * 128 + cg * 64 + m * 16 + l15;                     \
        AF[m] = *(const bf16x8*)&swc[row_ * 32 + qa * 8];                         \
    }                                                                             \
    _Pragma("unroll")                                                             \
    for (int n = 0; n < 6; ++n) {                                                 \
        const int P_ = (wrow * 3 + (n >> 1) + (KH)) * 34 + (n & 1) * 16 + l15 + (KW); \
        BF[n] = *(const bf16x8*)&sxc[P_ * 32 + ((qq ^ ((P_ >> 1) & 3)) << 3)];    \
    }                                                                             \
}
#define MFMA_ON(AF, BF) {                                                         \
    _Pragma("unroll")                                                             \
    for (int n = 0; n < 6; ++n)                                                   \
        _Pragma("unroll")                                                         \
        for (int m = 0; m < 4; ++m)                                               \
            acc[m][n] = __builtin_amdgcn_mfma_f32_16x16x32_bf16(AF[m], BF[n], acc[m][n], 0, 0, 0); \
}

// One barrier region per sub-step. WST: wbuf stage idx; WGI: global w index;
// DOW: stage w?; NX: x slices staged (0,1,3); VN_MAIN/VN_TAIL: drain counts.
#define SUBSTEP(KH, WST, WGI, DOW, NX, VDRAIN_MAIN, VDRAIN_TAIL) {                \
    const unsigned short* swc = s_w[(KH)];                                        \
    const unsigned short* sxc = s_x[c & 1];                                       \
    bf16x8 a0[4], b0[6], a1[4], b1[6], a2[4], b2[6];                              \
    LOADF(a0, b0, KH, 0);                                                         \
    LOADF(a1, b1, KH, 1);                                                         \
    if (DOW) {                                                                    \
        _Pragma("unroll")                                                         \
        for (int i = 0; i < 3; ++i)                                               \
            lds_load16(&s_w[(WST)][(size_t)(i * 512 + tid) * 8],                  \
                       wp + (size_t)(WGI) * 24576 + wbase[i]);                    \
    }                                                                             \
    if ((NX) == 3 && c < 7) {                                                     \
        _Pragma("unroll")                                                         \
        for (int i = 0; i < 3; ++i)                                               \
            lds_load16(&s_x[(c + 1) & 1][(size_t)(i * 512 + tid) * 8],            \
                       img + xg[i] + (c + 1) * 32);                               \
    }                                                                             \
    if ((NX) == 1 && c < 7)                                                       \
        lds_load16(&s_x[(c + 1) & 1][(size_t)(3 * 512 + tid) * 8],                \
                   img + xg[3] + (c + 1) * 32);                                   \
    MEMFENCE(); SB();                                                             \
    __builtin_amdgcn_s_setprio(1);                                                \
    asm volatile("s_waitcnt lgkmcnt(10)" ::: "memory"); SB();                     \
    MFMA_ON(a0, b0);                                                              \
    LOADF(a2, b2, KH, 2);                                                         \
    MEMFENCE(); SB();                                                             \
    asm volatile("s_waitcnt lgkmcnt(10)" ::: "memory"); SB();                     \
    MFMA_ON(a1, b1);                                                              \
    asm volatile("s_waitcnt lgkmcnt(0)" ::: "memory"); SB();                      \
    MFMA_ON(a2, b2);                                                              \
    __builtin_amdgcn_s_setprio(0);                                                \
    if (c < 7) { asm volatile("s_waitcnt vmcnt(" #VDRAIN_MAIN ")" ::: "memory"); }\
    else       { asm volatile("s_waitcnt vmcnt(" #VDRAIN_TAIL ")" ::: "memory"); }\
    SB();                                                                         \
    __builtin_amdgcn_s_barrier();                                                 \
    SB();                                                                         \
}

    for (int c = 0; c < 8; ++c) {
        SUBSTEP(0, 2, (3 * c + 2), true,      3, 6, 3)
        SUBSTEP(1, 0, (3 * c + 3), (c < 7),   1, 7, 0)
        SUBSTEP(2, 1, (3 * c + 4), (c < 7),   0, 3, 0)
    }
#undef SUBSTEP
#undef LOADF
#undef MFMA_ON

    // ---- epilogue (n-outer, m-inner for write combining) ----
    if constexpr (MODE == 0) {
        const float pw = prelu_w[0];
        unsigned short* aout = (unsigned short*)outp;
        #pragma unroll
        for (int n = 0; n < 6; ++n) {
            const int row_p = wrow * 3 + (n >> 1);
            const int col_p = (n & 1) * 16 + l15;
            size_t pix = ((size_t)(b * PH + R0 + row_p + 1)) * PW + (C0 + col_p + 1);
            #pragma unroll
            for (int m = 0; m < 4; ++m) {
                const int cb = blk_co + cg * 64 + m * 16 + qq * 4;
                float r[4];
                #pragma unroll
                for (int j = 0; j < 4; ++j) {
                    const int ch = cb + j;
                    float s = acc[m][n][j];
                    if (ch < 86)        r[j] = s >= 0.f ? s : pw * s;
                    else if (ch < 171)  r[j] = fmaxf(s, 0.f);
                    else {
                        float e = __expf(2.f * s);
                        r[j] = 1.f - 2.f / (e + 1.f);
                    }
                }
                ushort4 o;
                o.x = f2bf(r[0]); o.y = f2bf(r[1]); o.z = f2bf(r[2]); o.w = f2bf(r[3]);
                *(ushort4*)(aout + pix * 256 + cb) = o;
            }
        }
    } else {
        float* fout = (float*)outp;
        #pragma unroll
        for (int n = 0; n < 6; ++n) {
            const int row_p = wrow * 3 + (n >> 1);
            const int col_p = (n & 1) * 16 + l15;
            #pragma unroll
            for (int m = 0; m < 4; ++m) {
                const int cb = blk_co + cg * 64 + m * 16 + qq * 4;
                size_t base = ((size_t)(b * Cn + cb)) * HW + (size_t)(R0 + row_p) * Wn + (C0 + col_p);
                #pragma unroll
                for (int j = 0; j < 4; ++j)
                    fout[base + (size_t)j * HW] = acc[m][n][j] * 0.1f + xres[base + (size_t)j * HW];
            }
        }
    }
}

extern "C" void kernel_launch(void* const* d_in, const int* in_sizes, int n_in,
                              void* d_out, int out_size, void* d_ws, size_t ws_size,
                              hipStream_t stream) {
    const float* x  = (const float*)d_in[0];
    const float* w2 = (const float*)d_in[1];
    const float* w3 = (const float*)d_in[2];
    const float* pw = (const float*)d_in[3];
    float* out = (float*)d_out;
    char* ws = (char*)d_ws;

    // ws layout: a_cl (78,675,968 B) | wp2 (1,179,648 B) | wp3 (1,179,648 B)  = 81 MB
    unsigned short* a_cl = (unsigned short*)ws;
    unsigned short* wp2  = (unsigned short*)(ws + 78675968);
    unsigned short* wp3  = (unsigned short*)(ws + 78675968 + 1179648);
    // x_pad aliases d_out (78.7 MB <= 151 MB); dead before conv<1> writes d_out.
    unsigned short* x_pad = (unsigned short*)d_out;

    zero_border_k<<<776, 256, 0, stream>>>(x_pad);
    zero_border_k<<<776, 256, 0, stream>>>(a_cl);
    pack_w_k<true ><<<2304, 256, 0, stream>>>(w2, wp2);
    pack_w_k<false><<<2304, 256, 0, stream>>>(w3, wp3);
    transform_x_k<<<dim3(3, 96, 128), 256, 0, stream>>>(x, x_pad);

    conv_k<0><<<768, 512, 0, stream>>>(x_pad, wp2, pw, nullptr, (void*)a_cl);
    conv_k<1><<<768, 512, 0, stream>>>(a_cl, wp3, nullptr, x, (void*)out);
}

// Round 11
// 433.820 us; speedup vs baseline: 2.9864x; 2.9864x over previous
//
#include <hip/hip_runtime.h>
#include <math.h>

// ResBlock via bf16 MFMA implicit-GEMM conv3x3.
// R11: SMALL blocks, 4 blocks/CU, cross-block TLP for pipe overlap
// (R8-R10 post-mortem: every 1-block/CU schedule serialized LDS and MFMA
// bursts; in-block pipelining was repeatedly defeated by the register
// allocator - deleted at cap 128, spilled when pinned. m97's measured
// mechanism: multi-block residency overlaps pipes with zero reg pressure).
// Block: 256 thr (4 waves), 64co x 8x32 px, sub-step = (ci32,k9) slice.
// LDS 32.8KB: s_x single 24.6KB + s_w dbuf 2x4KB -> 4 blocks/CU.
// B=16, C=256, H=W=96. Padded channels-last bf16 intermediates [16][98][98][256].

#define Bn 16
#define Cn 256
#define Hn 96
#define Wn 96
#define PH 98
#define PW 98
#define HW (Hn*Wn)

typedef __bf16 bf16x8 __attribute__((ext_vector_type(8)));
typedef float  f32x4  __attribute__((ext_vector_type(4)));

__device__ __forceinline__ unsigned short f2bf(float f) {
    unsigned int u = __float_as_uint(f);
    unsigned int r = (u + 0x7fffu + ((u >> 16) & 1u)) >> 16;
    return (unsigned short)r;
}

__device__ __forceinline__ void lds_load16(void* lds, const void* g) {
    auto gp = (const __attribute__((address_space(1))) char*)(unsigned long long)(uintptr_t)g;
    auto lp = (__attribute__((address_space(3))) char*)(unsigned int)(uintptr_t)lds;
    __builtin_amdgcn_global_load_lds(gp, lp, 16, 0, 0);
}

#define SB() __builtin_amdgcn_sched_barrier(0)
#define MEMFENCE() asm volatile("" ::: "memory")

// ---- zero the padded border of a CL tensor ----
__global__ __launch_bounds__(256)
void zero_border_k(unsigned short* __restrict__ t) {
    int idx = blockIdx.x * 256 + threadIdx.x;      // 16*388*32 threads
    int oct = idx & 31;
    int rest = idx >> 5;
    int pidx = rest % 388;
    int b = rest / 388;
    int h, w;
    if (pidx < 98)       { h = 0;  w = pidx; }
    else if (pidx < 196) { h = 97; w = pidx - 98; }
    else if (pidx < 292) { h = pidx - 196 + 1; w = 0; }
    else                 { h = pidx - 292 + 1; w = 97; }
    size_t e = ((size_t)(b * PH + h) * PW + w) * 256 + oct * 8;
    *(uint4*)(t + e) = make_uint4(0u, 0u, 0u, 0u);
}

// ---- pack weights fp32 [co][ci][3][3] -> bf16 [cc][k9][c'][ci32] ----
template<bool PERM>
__global__ __launch_bounds__(256)
void pack_w_k(const float* __restrict__ w, unsigned short* __restrict__ wp) {
    int idx = blockIdx.x * 256 + threadIdx.x;      // 589824
    int ci_l = idx & 31;
    int c    = (idx >> 5) & 255;
    int v    = idx >> 13;          // 0..71
    int k9   = v % 9;
    int cc   = v / 9;
    int co;
    if (PERM) {
        co = (c < 86) ? c * 3 : (c < 171) ? (c - 86) * 3 + 1 : (c - 171) * 3 + 2;
    } else {
        co = c;
    }
    float val = w[((size_t)co * 256 + cc * 32 + ci_l) * 9 + k9];
    wp[idx] = f2bf(val);
}

// ---- x fp32 NCHW -> padded channels-last bf16 (interior only) ----
__global__ __launch_bounds__(256)
void transform_x_k(const float* __restrict__ x, unsigned short* __restrict__ xp) {
    __shared__ float s[32 * 33];
    const int t = threadIdx.x;
    const int col0 = blockIdx.x * 32;
    const int row  = blockIdx.y;
    const int z = blockIdx.z;
    const int b = z >> 3;
    const int ci0 = (z & 7) * 32;

    #pragma unroll
    for (int i = 0; i < 4; ++i) {
        int ci = i * 8 + (t >> 5);
        int px = t & 31;
        s[ci * 33 + px] = x[((size_t)(b * Cn + ci0 + ci)) * HW + row * Wn + col0 + px];
    }
    __syncthreads();
    const int px = t >> 3;
    const int c4 = (t & 7) * 4;
    ushort4 o;
    o.x = f2bf(s[(c4 + 0) * 33 + px]);
    o.y = f2bf(s[(c4 + 1) * 33 + px]);
    o.z = f2bf(s[(c4 + 2) * 33 + px]);
    o.w = f2bf(s[(c4 + 3) * 33 + px]);
    size_t e = ((size_t)(b * PH + row + 1) * PW + (col0 + px + 1)) * 256 + ci0 + c4;
    *(ushort4*)(xp + e) = o;
}

// ---- MFMA conv3x3, 4-blocks-per-CU TLP design ----
// 256 threads (4 waves). Block: 64 co x (8 rows x 32 cols).
// Wave wv owns rows wv*2..wv*2+1; frags: m=4 (16co), n=4 (2row x 2colhalf).
// 72 sub-steps s = c*9+k9: read s_w[s&1] slice [co64][ci32] + s_x halo
// (10x34 px)[ci32 chunk c]; 16 MFMA; stage w(s+1) to s_w[(s+1)&1] (drained
// same sub-step, L2-hot); x(c+1) staged in one batch at chunk boundary
// (exposure hidden by the other 3 resident blocks).
// Staging via global_load_lds, PRE-SWIZZLED SOURCE (rule #21), involution
// phys16Bslot = logical ^ ((logical>>3)&3); reads apply the same XOR.
template<int MODE>
__global__ __launch_bounds__(256, 4)
void conv_k(const unsigned short* __restrict__ in_cl,
            const unsigned short* __restrict__ wp,
            const float* __restrict__ prelu_w,
            const float* __restrict__ xres,
            void* __restrict__ outp)
{
    __shared__ unsigned short s_x[1536 * 8];     // 24576 B: 340px (10x34) + trash
    __shared__ unsigned short s_w[2][256 * 8];   // 2 x 4096 B: [co64][ci32] slice

    const int tid = threadIdx.x;
    const int bid = blockIdx.x;
    // XCD-chunked bijective swizzle (2304 = 8 * 288); co-group fastest so the
    // 4 co-groups sharing one x-tile land on the same XCD L2.
    const int wg = (bid & 7) * 288 + (bid >> 3);
    const int co_base = (wg & 3) * 64;
    const int t2 = wg >> 2;            // 0..575
    const int tile = t2 % 36;
    const int b = t2 / 36;
    const int R0 = (tile / 3) * 8;     // image/halo base row (12 row-tiles)
    const int C0 = (tile % 3) * 32;

    const int lane = tid & 63;
    const int wv = tid >> 6;           // row-pair 0..3
    const int l15 = lane & 15;
    const int qq = lane >> 4;
    const int qa = qq ^ ((l15 >> 1) & 3);

    const unsigned short* img = in_cl + (size_t)b * PH * PW * 256;

    // ---- staging maps (gl_lds dest linear; source pre-swizzled) ----
    // x: 340 px * 4 parts = 1360 logical slots; 6 issues/thread (1536 dests,
    // slots >=1360 clamp source; dests land in the trash region 1360..1535).
    int xg[6];
    #pragma unroll
    for (int i = 0; i < 6; ++i) {
        int slot = i * 256 + tid;
        int lsl = slot ^ ((slot >> 3) & 3);    // involution
        if (lsl > 1359) lsl = 1359;
        int p = lsl >> 2;
        int pr = p / 34, pc = p - pr * 34;
        xg[i] = ((R0 + pr) * PW + (C0 + pc)) * 256 + (lsl & 3) * 8;
    }
    // w slice: 64 co * 4 parts = 256 slots, exactly 1/thread
    int wroff;
    {
        int lsl = tid ^ ((tid >> 3) & 3);
        wroff = (co_base + (lsl >> 2)) * 32 + (lsl & 3) * 8;
    }

    f32x4 acc[4][4];
    #pragma unroll
    for (int m = 0; m < 4; ++m)
        #pragma unroll
        for (int n = 0; n < 4; ++n) acc[m][n] = 0.f;

    // ---- prologue: w(0) -> s_w[0], x(0) -> s_x ----
    lds_load16(&s_w[0][(size_t)tid * 8], wp + wroff);
    #pragma unroll
    for (int i = 0; i < 6; ++i)
        lds_load16(&s_x[(size_t)(i * 256 + tid) * 8], img + xg[i]);
    MEMFENCE(); SB();
    asm volatile("s_waitcnt vmcnt(0)" ::: "memory");
    SB();
    __builtin_amdgcn_s_barrier();
    SB();

    for (int c = 0; c < 8; ++c) {
        #pragma unroll
        for (int k9 = 0; k9 < 9; ++k9) {
            const int s = c * 9 + k9;
            const int kh = k9 / 3, kw = k9 - 3 * kh;
            const unsigned short* swc = s_w[s & 1];

            // stage w(s+1) (drained at end of this sub-step; L2-hot)
            if (c < 7 || k9 < 8)
                lds_load16(&s_w[(s + 1) & 1][(size_t)tid * 8],
                           wp + (size_t)(s + 1) * 8192 + wroff);
            MEMFENCE(); SB();

            bf16x8 af[4], bf[4];
            #pragma unroll
            for (int m = 0; m < 4; ++m)
                af[m] = *(const bf16x8*)&swc[(m * 16 + l15) * 32 + qa * 8];
            #pragma unroll
            for (int n = 0; n < 4; ++n) {
                const int P = (wv * 2 + (n >> 1) + kh) * 34 + (n & 1) * 16 + l15 + kw;
                bf[n] = *(const bf16x8*)&s_x[P * 32 + ((qq ^ ((P >> 1) & 3)) << 3)];
            }
            __builtin_amdgcn_s_setprio(1);
            #pragma unroll
            for (int n = 0; n < 4; ++n)
                #pragma unroll
                for (int m = 0; m < 4; ++m)
                    acc[m][n] = __builtin_amdgcn_mfma_f32_16x16x32_bf16(af[m], bf[n], acc[m][n], 0, 0, 0);
            __builtin_amdgcn_s_setprio(0);
            SB();

            if (k9 < 8) {
                asm volatile("s_waitcnt vmcnt(0)" ::: "memory");  // w(s+1) landed
                SB();
                __builtin_amdgcn_s_barrier();
                SB();
            }
        }
        // ---- chunk boundary: restage s_x with chunk c+1 ----
        __builtin_amdgcn_s_barrier();        // all waves done reading s_x(c)
        SB();
        if (c < 7) {
            #pragma unroll
            for (int i = 0; i < 6; ++i)
                lds_load16(&s_x[(size_t)(i * 256 + tid) * 8],
                           img + xg[i] + (c + 1) * 32);
            MEMFENCE(); SB();
        }
        asm volatile("s_waitcnt vmcnt(0)" ::: "memory");  // w + x batch landed
        SB();
        __builtin_amdgcn_s_barrier();
        SB();
    }

    // ---- epilogue (n-outer, m-inner for write combining) ----
    if constexpr (MODE == 0) {
        const float pw = prelu_w[0];
        unsigned short* aout = (unsigned short*)outp;
        #pragma unroll
        for (int n = 0; n < 4; ++n) {
            const int row_p = wv * 2 + (n >> 1);
            const int col_p = (n & 1) * 16 + l15;
            size_t pix = ((size_t)(b * PH + R0 + row_p + 1)) * PW + (C0 + col_p + 1);
            #pragma unroll
            for (int m = 0; m < 4; ++m) {
                const int cb = co_base + m * 16 + qq * 4;
                float r[4];
                #pragma unroll
                for (int j = 0; j < 4; ++j) {
                    const int ch = cb + j;
                    float s = acc[m][n][j];
                    if (ch < 86)        r[j] = s >= 0.f ? s : pw * s;
                    else if (ch < 171)  r[j] = fmaxf(s, 0.f);
                    else {
                        float e = __expf(2.f * s);
                        r[j] = 1.f - 2.f / (e + 1.f);
                    }
                }
                ushort4 o;
                o.x = f2bf(r[0]); o.y = f2bf(r[1]); o.z = f2bf(r[2]); o.w = f2bf(r[3]);
                *(ushort4*)(aout + pix * 256 + cb) = o;
            }
        }
    } else {
        float* fout = (float*)outp;
        #pragma unroll
        for (int n = 0; n < 4; ++n) {
            const int row_p = wv * 2 + (n >> 1);
            const int col_p = (n & 1) * 16 + l15;
            #pragma unroll
            for (int m = 0; m < 4; ++m) {
                const int cb = co_base + m * 16 + qq * 4;
                size_t base = ((size_t)(b * Cn + cb)) * HW + (size_t)(R0 + row_p) * Wn + (C0 + col_p);
                #pragma unroll
                for (int j = 0; j < 4; ++j)
                    fout[base + (size_t)j * HW] = acc[m][n][j] * 0.1f + xres[base + (size_t)j * HW];
            }
        }
    }
}

extern "C" void kernel_launch(void* const* d_in, const int* in_sizes, int n_in,
                              void* d_out, int out_size, void* d_ws, size_t ws_size,
                              hipStream_t stream) {
    const float* x  = (const float*)d_in[0];
    const float* w2 = (const float*)d_in[1];
    const float* w3 = (const float*)d_in[2];
    const float* pw = (const float*)d_in[3];
    float* out = (float*)d_out;
    char* ws = (char*)d_ws;

    // ws layout: a_cl (78,675,968 B) | wp2 (1,179,648 B) | wp3 (1,179,648 B)  = 81 MB
    unsigned short* a_cl = (unsigned short*)ws;
    unsigned short* wp2  = (unsigned short*)(ws + 78675968);
    unsigned short* wp3  = (unsigned short*)(ws + 78675968 + 1179648);
    // x_pad aliases d_out (78.7 MB <= 151 MB); dead before conv<1> writes d_out.
    unsigned short* x_pad = (unsigned short*)d_out;

    zero_border_k<<<776, 256, 0, stream>>>(x_pad);
    zero_border_k<<<776, 256, 0, stream>>>(a_cl);
    pack_w_k<true ><<<2304, 256, 0, stream>>>(w2, wp2);
    pack_w_k<false><<<2304, 256, 0, stream>>>(w3, wp3);
    transform_x_k<<<dim3(3, 96, 128), 256, 0, stream>>>(x, x_pad);

    conv_k<0><<<2304, 256, 0, stream>>>(x_pad, wp2, pw, nullptr, (void*)a_cl);
    conv_k<1><<<2304, 256, 0, stream>>>(a_cl, wp3, nullptr, x, (void*)out);
}